// Round 7
// baseline (117.922 us; speedup 1.0000x reference)
//
#include <hip/hip_runtime.h>
#include <math.h>

// BaseHybridHead, 3 stream-ordered kernels (R14):
//  KA: pre-GEMM + rank-1 expand -> psi0 (8192x1024 f16); Arm rows (1024x1024
//      f16); zero z[8192][10].                        [R7-verified, 2048 blocks]
//  KB: MFMA GEMM psif = psi0 @ Arm^T, 128x256 tile, 8 waves. R14 on top of
//      R13: (a) XCD-affinity remap mB=(p%8)+8*(p>>5), nB=(p>>3)&3 -> each
//      XCD's 32 blocks share 8 psi0 slices + 4 Arm slices = 4MB = its L2;
//      (b) 3-deep LDS pipeline (3x48KB=144KB), stage t+2 while computing t,
//      steady-state s_waitcnt vmcnt(12) -> 2 compute phases (~700cy) cover
//      L3 latency. Explicit pointer rotation (no runtime-indexed arrays).
//      Fused +-square measurement epilogue [R13-verified signs].
//  KC: out = z @ Wpost^T + bpost.                     [R6-verified]
//  Fallback: R1-verified single kernel for off-shape.

#define NQ   10
#define NREG 16
#define DIM  1024

typedef _Float16 f16;
typedef _Float16 f16x8 __attribute__((ext_vector_type(8)));
typedef float    f32x4 __attribute__((ext_vector_type(4)));

// ---------------------------------------------------------------- gate ops
template<int BB>
__device__ __forceinline__ void ry_lane(float (&s)[NREG], int lane, float c, float si) {
    float sgn = ((lane >> BB) & 1) ? si : -si;
    #pragma unroll
    for (int r = 0; r < NREG; ++r) {
        float o = __shfl_xor(s[r], 1 << BB);
        s[r] = fmaf(sgn, o, c * s[r]);
    }
}
template<int P>
__device__ __forceinline__ void ry_reg(float (&s)[NREG], float c, float si) {
    const int m = 1 << P;
    #pragma unroll
    for (int r = 0; r < NREG; ++r) {
        if ((r & m) == 0) {
            float a = s[r], b = s[r + m];
            s[r]     = fmaf(c, a, -si * b);
            s[r + m] = fmaf(si, a,  c * b);
        }
    }
}
__device__ __forceinline__ void cnot_5_6(float (&s)[NREG], int lane) {
    bool sel = (lane & 1) != 0;
    #pragma unroll
    for (int r = 0; r < 8; ++r) {
        float a = s[r], b = s[r + 8];
        s[r]     = sel ? b : a;
        s[r + 8] = sel ? a : b;
    }
}
template<int PC, int PT>
__device__ __forceinline__ void cnot_reg(float (&s)[NREG]) {
    #pragma unroll
    for (int r = 0; r < NREG; ++r) {
        if (((r >> PC) & 1) && !((r >> PT) & 1)) {
            float t = s[r];
            s[r] = s[r ^ (1 << PT)];
            s[r ^ (1 << PT)] = t;
        }
    }
}
__device__ __forceinline__ void perm_even(float (&s)[NREG], int lane) {
    int src = lane ^ (((((lane >> 5) & 1) << 4)) | ((((lane >> 3) & 1) << 2)) | (((lane >> 1) & 1)));
    #pragma unroll
    for (int r = 0; r < NREG; ++r) s[r] = __shfl(s[r], src);
}
__device__ __forceinline__ void perm_odd(float (&s)[NREG], int lane) {
    int src = lane ^ (((((lane >> 4) & 1) << 3)) | ((((lane >> 2) & 1) << 1)));
    #pragma unroll
    for (int r = 0; r < NREG; ++r) s[r] = __shfl(s[r], src);
}

#define APPLY_RY_ALL(CARR, SARR, BASE)                                        \
    { float c_, s_;                                                           \
      c_=__shfl(CARR,(BASE)+0); s_=__shfl(SARR,(BASE)+0); ry_lane<5>(s,lane,c_,s_); \
      c_=__shfl(CARR,(BASE)+1); s_=__shfl(SARR,(BASE)+1); ry_lane<4>(s,lane,c_,s_); \
      c_=__shfl(CARR,(BASE)+2); s_=__shfl(SARR,(BASE)+2); ry_lane<3>(s,lane,c_,s_); \
      c_=__shfl(CARR,(BASE)+3); s_=__shfl(SARR,(BASE)+3); ry_lane<2>(s,lane,c_,s_); \
      c_=__shfl(CARR,(BASE)+4); s_=__shfl(SARR,(BASE)+4); ry_lane<1>(s,lane,c_,s_); \
      c_=__shfl(CARR,(BASE)+5); s_=__shfl(SARR,(BASE)+5); ry_lane<0>(s,lane,c_,s_); \
      c_=__shfl(CARR,(BASE)+6); s_=__shfl(SARR,(BASE)+6); ry_reg<3>(s,c_,s_);       \
      c_=__shfl(CARR,(BASE)+7); s_=__shfl(SARR,(BASE)+7); ry_reg<2>(s,c_,s_);       \
      c_=__shfl(CARR,(BASE)+8); s_=__shfl(SARR,(BASE)+8); ry_reg<1>(s,c_,s_);       \
      c_=__shfl(CARR,(BASE)+9); s_=__shfl(SARR,(BASE)+9); ry_reg<0>(s,c_,s_); }

__device__ __forceinline__ void async16(const void* g, void* l) {
    __builtin_amdgcn_global_load_lds(
        (const __attribute__((address_space(1))) void*)g,
        (__attribute__((address_space(3))) void*)l, 16, 0, 0);
}

// raw barrier + scheduling fence; NO compiler vmcnt(0) drain.
#define BARRIER() do { __builtin_amdgcn_s_barrier(); __builtin_amdgcn_sched_barrier(0); } while (0)
#define VMCNT12() asm volatile("s_waitcnt vmcnt(12)" ::: "memory")
#define VMCNT6()  asm volatile("s_waitcnt vmcnt(6)" ::: "memory")
#define VMCNT0()  asm volatile("s_waitcnt vmcnt(0)" ::: "memory")

// ---------------------------------------------------------------- KA  [R7-verified]
// grid 2048 x 256: one sample per wave; blocks 0..511 also build 2 Arm rows each.
__global__ __launch_bounds__(256) void ka_prepare(
    const float* __restrict__ X, const float* __restrict__ Wpre,
    const float* __restrict__ bpre, const float* __restrict__ qp,
    f16* __restrict__ psi0, f16* __restrict__ Arm, float* __restrict__ z, int B)
{
    const int tid = threadIdx.x, lane = tid & 63, wv = tid >> 6;

    // ---- zero z accumulator (8192*10 floats; 2048x256 threads cover 1/thread)
    {
        int idx = blockIdx.x * 256 + tid;
        if (idx < 8192 * NQ) z[idx] = 0.0f;
    }

    // ---- psi0: one sample per wave
    {
        int sample = blockIdx.x * 4 + wv;
        if (sample < B) {
            const float* xrow = X + (size_t)sample * 512;
            float4 x0 = ((const float4*)xrow)[lane];
            float4 x1 = ((const float4*)xrow)[64 + lane];
            float acc[NQ];
            #pragma unroll
            for (int q = 0; q < NQ; ++q) {
                const float* wr = Wpre + q * 512;
                float4 w0 = ((const float4*)wr)[lane];
                float4 w1 = ((const float4*)wr)[64 + lane];
                float a = x0.x * w0.x;
                a = fmaf(x0.y, w0.y, a); a = fmaf(x0.z, w0.z, a); a = fmaf(x0.w, w0.w, a);
                a = fmaf(x1.x, w1.x, a); a = fmaf(x1.y, w1.y, a);
                a = fmaf(x1.z, w1.z, a); a = fmaf(x1.w, w1.w, a);
                acc[q] = a;
            }
            #pragma unroll
            for (int q = 0; q < NQ; ++q) {
                float v = acc[q];
                #pragma unroll
                for (int d = 32; d >= 1; d >>= 1) v += __shfl_xor(v, d);
                acc[q] = v;
            }
            float pre = acc[0];
            #pragma unroll
            for (int q = 1; q < NQ; ++q) pre = (lane == q) ? acc[q] : pre;
            float c45 = 0.0f, s45 = 0.0f;
            if (lane < NQ) {
                float th = tanhf(pre + bpre[lane]) * 1.5707963267948966f;
                sincosf(0.5f * th + 0.7853981633974483f, &s45, &c45);
            }
            float lv = 1.0f;
            #pragma unroll
            for (int w = 0; w < 6; ++w) {
                float f0 = __shfl(c45, w), f1 = __shfl(s45, w);
                lv *= ((lane >> (5 - w)) & 1) ? f1 : f0;
            }
            float c6 = __shfl(c45, 6), s6 = __shfl(s45, 6);
            float c7 = __shfl(c45, 7), s7 = __shfl(s45, 7);
            float c8 = __shfl(c45, 8), s8 = __shfl(s45, 8);
            float c9 = __shfl(c45, 9), s9 = __shfl(s45, 9);
            float g01[4] = {c6 * c7, c6 * s7, s6 * c7, s6 * s7};
            float g23[4] = {c8 * c9, c8 * s9, s8 * c9, s8 * s9};
            union { f16 h[16]; float4 v[2]; } u;
            #pragma unroll
            for (int r = 0; r < NREG; ++r)
                u.h[r] = (f16)(lv * g01[r >> 2] * g23[r & 3]);
            float4* dst = (float4*)((char*)psi0 + (size_t)sample * 2048 + lane * 32);
            dst[0] = u.v[0];
            dst[1] = u.v[1];
        }
    }

    // ---- Arm rows: blocks 0..511, waves 0,1 build row (blockIdx*2 + wv)
    if (wv < 2) {
        int row = blockIdx.x * 2 + wv;
        if (row < DIM) {
            float cw = 1.0f, swn = 0.0f;
            if (lane < 60) {
                float s_, c_;
                sincosf(0.5f * qp[10 + lane], &s_, &c_);
                cw = c_; swn = -s_;
            }
            float s[NREG];
            int srcLane = row >> 4, srcReg = row & 15;
            #pragma unroll
            for (int r = 0; r < NREG; ++r)
                s[r] = (lane == srcLane && r == srcReg) ? 1.0f : 0.0f;
            for (int kk = 6; kk >= 1; --kk) {
                APPLY_RY_ALL(cw, swn, (kk - 1) * 10);
                perm_odd(s, lane);
                cnot_5_6(s, lane);
                cnot_reg<2, 1>(s);
                perm_even(s, lane);
                cnot_reg<3, 2>(s);
                cnot_reg<1, 0>(s);
            }
            union { f16 h[16]; float4 v[2]; } u;
            #pragma unroll
            for (int r = 0; r < NREG; ++r) u.h[r] = (f16)s[r];
            float4* dst = (float4*)((char*)Arm + (size_t)row * 2048 + lane * 32);
            dst[0] = u.v[0];
            dst[1] = u.v[1];
        }
    }
}

// ---------------------------------------------------------------- KB  [R14]
// 128x256 tile, BK=64, grid 256, 512 threads = 8 waves (2M x 4N, wave 64x64).
// XCD-affinity remap + 3-deep 144KB LDS pipeline, counted vmcnt(12/6/0).
__global__ __launch_bounds__(512) void kb_gemm_measure(
    const f16* __restrict__ psi0, const f16* __restrict__ Arm,
    float* __restrict__ z)
{
    __shared__ __align__(16) char smem[147456];  // 3 x (As 16K | Bs 32K); zbuf reuse
    const int tid = threadIdx.x, lane = tid & 63, wv = tid >> 6;
    // XCD-affinity: p%8 = XCD (round-robin dispatch). Same-mB siblings share XCD.
    const int p = blockIdx.x;
    const int mB = (p & 7) + 8 * (p >> 5), nB = (p >> 3) & 3;
    const size_t tM = (size_t)mB * 128, tN = (size_t)nB * 256;
    f16* As_[3] = { (f16*)smem,           (f16*)(smem + 49152), (f16*)(smem + 98304) };
    f16* Bs_[3] = { (f16*)(smem + 16384), (f16*)(smem + 65536), (f16*)(smem + 114688) };
    const int wm = (wv >> 2) * 64, wn = (wv & 3) * 64;

    f32x4 acc[4][4] = {};

    // staging: A 1024 slots (2/thread), B 2048 slots (4/thread); 8-f16 granules,
    // XOR-swizzled: LDS[row][gp] holds global granule gp^(row&7).
    const f16* ga[2]; int ldsoA[2];
    const f16* gb[4]; int ldsoB[4];
    #pragma unroll
    for (int q = 0; q < 2; ++q) {
        int slot = q * 512 + tid;
        int row = slot >> 3, gp = slot & 7, g = gp ^ (row & 7);
        ga[q] = psi0 + (tM + row) * 1024 + g * 8;
        ldsoA[q] = slot * 16;
    }
    #pragma unroll
    for (int q = 0; q < 4; ++q) {
        int slot = q * 512 + tid;
        int row = slot >> 3, gp = slot & 7, g = gp ^ (row & 7);
        gb[q] = Arm + (tN + row) * 1024 + g * 8;
        ldsoB[q] = slot * 16;
    }

    auto stage = [&](f16* Ab, f16* Bb, int kt) {   // 6 loads/wave
        #pragma unroll
        for (int q = 0; q < 2; ++q) async16(ga[q] + kt, (char*)Ab + ldsoA[q]);
        #pragma unroll
        for (int q = 0; q < 4; ++q) async16(gb[q] + kt, (char*)Bb + ldsoB[q]);
    };
    auto compute = [&](const f16* Ab, const f16* Bb) {
        #pragma unroll
        for (int ks = 0; ks < 2; ++ks) {
            f16x8 af[4], bf[4];
            const int gpb = ks * 4 + (lane >> 4);
            const int gpx = gpb ^ (lane & 7);
            #pragma unroll
            for (int i = 0; i < 4; ++i) {
                int rowA = wm + i * 16 + (lane & 15);
                af[i] = *(const f16x8*)(Ab + rowA * 64 + gpx * 8);
            }
            #pragma unroll
            for (int j = 0; j < 4; ++j) {
                int rowB = wn + j * 16 + (lane & 15);
                bf[j] = *(const f16x8*)(Bb + rowB * 64 + gpx * 8);
            }
            #pragma unroll
            for (int i = 0; i < 4; ++i)
                #pragma unroll
                for (int j = 0; j < 4; ++j)
                    acc[i][j] = __builtin_amdgcn_mfma_f32_16x16x32_f16(af[i], bf[j], acc[i][j], 0, 0, 0);
        }
    };

    // 3-deep pipeline over 16 K-tiles (kt = t*64). Explicit pointer rotation.
    f16 *Ac = As_[0], *Bc = Bs_[0];   // current (tile t)
    f16 *An = As_[1], *Bn = Bs_[1];   // next    (tile t+1)
    f16 *Af = As_[2], *Bf = Bs_[2];   // far     (tile t+2, being staged)
    stage(Ac, Bc, 0);
    stage(An, Bn, 64);
    #pragma unroll 1
    for (int t = 0; t < 14; ++t) {
        stage(Af, Bf, (t + 2) * 64);  // 18 in flight
        VMCNT12();                    // own 6 oldest (tile t) retired
        BARRIER();                    // all waves' tile-t loads in LDS
        compute(Ac, Bc);
        BARRIER();                    // tile-t buffer free for reuse
        f16* ta = Ac; f16* tb = Bc;
        Ac = An; Bc = Bn; An = Af; Bn = Bf; Af = ta; Bf = tb;
    }
    VMCNT6();  BARRIER(); compute(Ac, Bc); BARRIER();   // tile 14
    VMCNT0();  BARRIER(); compute(An, Bn);              // tile 15

    // ---- fused +-square measurement epilogue [R13-verified] ----
    // psif col n = tN + wn + j*16 + (lane&15): n9:8 <- nB, n7:6 <- wv&3,
    // n5:4 <- j, n3:0 <- lane&15. wires 0..9 <- n bits 9..0.
    __syncthreads();  // done with LDS; reuse as zbuf[4][128][10] f32 (20KB)
    float* zbuf = (float*)smem;
    float* zb = zbuf + (wv & 3) * 1280;
    const float sg0 = (nB & 2)        ? -1.0f : 1.0f;  // wire0 <- n9
    const float sg1 = (nB & 1)        ? -1.0f : 1.0f;  // wire1 <- n8
    const float sg2 = ((wv >> 1) & 1) ? -1.0f : 1.0f;  // wire2 <- n7
    const float sg3 = (wv & 1)        ? -1.0f : 1.0f;  // wire3 <- n6

    #pragma unroll
    for (int i = 0; i < 4; ++i) {
        #pragma unroll
        for (int t = 0; t < 4; ++t) {
            float p0 = acc[i][0][t] * acc[i][0][t];
            float p1 = acc[i][1][t] * acc[i][1][t];
            float p2 = acc[i][2][t] * acc[i][2][t];
            float p3 = acc[i][3][t] * acc[i][3][t];
            float t0  = (p0 + p1) + (p2 + p3);
            float tw5 = (p0 - p1) + (p2 - p3);  // wire5 <- n4 = j&1
            float tw4 = (p0 + p1) - (p2 + p3);  // wire4 <- n5 = j>>1
            // butterfly over lane bits 0..3 = n[3..0] -> wires 6,7,8,9
            float s1 = __shfl_xor(t0, 1);
            float Av = t0 + s1;
            float Bv = (lane & 1) ? s1 - t0 : t0 - s1;
            float sA = __shfl_xor(Av, 2), sB = __shfl_xor(Bv, 2);
            float AP = Av + sA;
            float AM = (lane & 2) ? sA - Av : Av - sA;
            float BP = Bv + sB;
            float sAP = __shfl_xor(AP, 4), sAM = __shfl_xor(AM, 4), sBP = __shfl_xor(BP, 4);
            float APP = AP + sAP;
            float APM = (lane & 4) ? sAP - AP : AP - sAP;
            float AMP = AM + sAM;
            float BPP = BP + sBP;
            float a1 = __shfl_xor(APP, 8), a2 = __shfl_xor(APM, 8);
            float a3 = __shfl_xor(AMP, 8), a4 = __shfl_xor(BPP, 8);
            float T0 = APP + a1;
            float S6 = (lane & 8) ? a1 - APP : APP - a1;
            float S7 = APM + a2;
            float S8 = AMP + a3;
            float S9 = BPP + a4;
            float T5 = tw5, T4 = tw4;
            T5 += __shfl_xor(T5, 1); T5 += __shfl_xor(T5, 2);
            T5 += __shfl_xor(T5, 4); T5 += __shfl_xor(T5, 8);
            T4 += __shfl_xor(T4, 1); T4 += __shfl_xor(T4, 2);
            T4 += __shfl_xor(T4, 4); T4 += __shfl_xor(T4, 8);
            if ((lane & 15) == 0) {
                int row = wm + i * 16 + (lane >> 4) * 4 + t;
                float* d = zb + row * 10;
                d[0] = sg0 * T0; d[1] = sg1 * T0; d[2] = sg2 * T0; d[3] = sg3 * T0;
                d[4] = T4; d[5] = T5;
                d[6] = S6; d[7] = S7; d[8] = S8; d[9] = S9;
            }
        }
    }
    __syncthreads();
    // combine 4 col-quarters, atomic-accumulate into z[tM+row][10]
    for (int idx = tid; idx < 1280; idx += 512) {
        float v = (zbuf[idx] + zbuf[1280 + idx]) + (zbuf[2560 + idx] + zbuf[3840 + idx]);
        int row = idx / 10, w = idx - row * 10;
        atomicAdd(&z[((size_t)tM + row) * 10 + w], v);
    }
}

// ---------------------------------------------------------------- KC  [R6-verified]
__global__ __launch_bounds__(256) void kc_post(
    const float* __restrict__ z, const float* __restrict__ Wpost,
    const float* __restrict__ bpost, float* __restrict__ out, int B)
{
    int gid = blockIdx.x * 256 + threadIdx.x;
    if (gid >= B) return;
    const float* zp = z + (size_t)gid * NQ;
    float o0 = bpost[0], o1 = bpost[1];
    #pragma unroll
    for (int w = 0; w < NQ; ++w) {
        float zw = zp[w];
        o0 = fmaf(zw, Wpost[w], o0);
        o1 = fmaf(zw, Wpost[NQ + w], o1);
    }
    out[(size_t)gid * 2 + 0] = o0;
    out[(size_t)gid * 2 + 1] = o1;
}

// ---------------------------------------------------------------- fallback (R1, verified)
template<int BC, int BT>
__device__ __forceinline__ void cnot_lane(float (&s)[NREG], int lane) {
    int src = ((lane >> BC) & 1) ? (lane ^ (1 << BT)) : lane;
    #pragma unroll
    for (int r = 0; r < NREG; ++r) s[r] = __shfl(s[r], src);
}

__global__ __launch_bounds__(256) void hybrid_head_fallback(
    const float* __restrict__ X, const float* __restrict__ Wpre,
    const float* __restrict__ bpre, const float* __restrict__ qp,
    const float* __restrict__ Wpost, const float* __restrict__ bpost,
    float* __restrict__ out, int B)
{
    const int lane = threadIdx.x & 63;
    const int wave = threadIdx.x >> 6;
    const int sample = blockIdx.x * 4 + wave;
    if (sample >= B) return;

    const float* xrow = X + (size_t)sample * 512;
    float4 x0 = ((const float4*)xrow)[lane];
    float4 x1 = ((const float4*)xrow)[64 + lane];
    float acc[NQ];
    #pragma unroll
    for (int q = 0; q < NQ; ++q) {
        const float* wr = Wpre + q * 512;
        float4 w0 = ((const float4*)wr)[lane];
        float4 w1 = ((const float4*)wr)[64 + lane];
        float a = x0.x * w0.x;
        a = fmaf(x0.y, w0.y, a); a = fmaf(x0.z, w0.z, a); a = fmaf(x0.w, w0.w, a);
        a = fmaf(x1.x, w1.x, a); a = fmaf(x1.y, w1.y, a);
        a = fmaf(x1.z, w1.z, a); a = fmaf(x1.w, w1.w, a);
        acc[q] = a;
    }
    #pragma unroll
    for (int q = 0; q < NQ; ++q) {
        float v = acc[q];
        #pragma unroll
        for (int d = 32; d >= 1; d >>= 1) v += __shfl_xor(v, d);
        acc[q] = v;
    }
    float pre = acc[0];
    #pragma unroll
    for (int q = 1; q < NQ; ++q) pre = (lane == q) ? acc[q] : pre;
    float cth = 1.0f, sth = 0.0f;
    if (lane < NQ) {
        float th = tanhf(pre + bpre[lane]) * 1.5707963267948966f;
        sincosf(0.5f * th, &sth, &cth);
    }
    float cw = 1.0f, sw = 0.0f;
    if (lane < 60) sincosf(0.5f * qp[10 + lane], &sw, &cw);

    float s[NREG];
    #pragma unroll
    for (int r = 0; r < NREG; ++r) s[r] = 0.03125f;
    APPLY_RY_ALL(cth, sth, 0);
    for (int k = 0; k < 6; ++k) {
        perm_even(s, lane);
        cnot_reg<3, 2>(s);
        cnot_reg<1, 0>(s);
        perm_odd(s, lane);
        cnot_5_6(s, lane);
        cnot_reg<2, 1>(s);
        APPLY_RY_ALL(cw, sw, k * 10);
    }
    float p[NREG], tot = 0.0f;
    #pragma unroll
    for (int r = 0; r < NREG; ++r) { p[r] = s[r] * s[r]; tot += p[r]; }
    float z[NQ];
    #pragma unroll
    for (int w = 0; w < 6; ++w) z[w] = ((lane >> (5 - w)) & 1) ? -tot : tot;
    z[6] = z[7] = z[8] = z[9] = 0.0f;
    #pragma unroll
    for (int r = 0; r < NREG; ++r) {
        z[6] += ((r >> 3) & 1) ? -p[r] : p[r];
        z[7] += ((r >> 2) & 1) ? -p[r] : p[r];
        z[8] += ((r >> 1) & 1) ? -p[r] : p[r];
        z[9] += ((r >> 0) & 1) ? -p[r] : p[r];
    }
    #pragma unroll
    for (int w = 0; w < NQ; ++w) {
        float v = z[w];
        #pragma unroll
        for (int d = 32; d >= 1; d >>= 1) v += __shfl_xor(v, d);
        z[w] = v;
    }
    if (lane < 2) {
        const float* wp = Wpost + lane * NQ;
        float o = bpost[lane];
        #pragma unroll
        for (int w = 0; w < NQ; ++w) o = fmaf(z[w], wp[w], o);
        out[(size_t)sample * 2 + lane] = o;
    }
}

// ---------------------------------------------------------------- launch
extern "C" void kernel_launch(void* const* d_in, const int* in_sizes, int n_in,
                              void* d_out, int out_size, void* d_ws, size_t ws_size,
                              hipStream_t stream) {
    const float* X     = (const float*)d_in[0];
    const float* Wpre  = (const float*)d_in[1];
    const float* bpre  = (const float*)d_in[2];
    const float* qp    = (const float*)d_in[3];
    const float* Wpost = (const float*)d_in[4];
    const float* bpost = (const float*)d_in[5];
    float* out = (float*)d_out;
    int B = in_sizes[0] / 512;  // 8192

    size_t psi0_b = (size_t)B * DIM * sizeof(f16);      // 16 MB
    size_t arm_b  = (size_t)DIM * DIM * sizeof(f16);    // 2 MB
    size_t z_b    = (size_t)B * NQ * sizeof(float);     // 320 KB
    size_t need = psi0_b + arm_b + z_b;

    if (B != 8192 || ws_size < need) {
        hipLaunchKernelGGL(hybrid_head_fallback, dim3((B + 3) / 4), dim3(256), 0, stream,
                           X, Wpre, bpre, qp, Wpost, bpost, out, B);
        return;
    }

    char* ws = (char*)d_ws;
    f16*   psi0 = (f16*)ws;
    f16*   Arm  = (f16*)(ws + psi0_b);
    float* z    = (float*)(ws + psi0_b + arm_b);

    hipLaunchKernelGGL(ka_prepare, dim3(2048), dim3(256), 0, stream,
                       X, Wpre, bpre, qp, psi0, Arm, z, B);
    hipLaunchKernelGGL(kb_gemm_measure, dim3(256), dim3(512), 0, stream,
                       psi0, Arm, z);
    hipLaunchKernelGGL(kc_post, dim3(32), dim3(256), 0, stream,
                       z, Wpost, bpost, out, B);
}

// Round 10
// 116.602 us; speedup vs baseline: 1.0113x; 1.0113x over previous
//
#include <hip/hip_runtime.h>
#include <math.h>

// BaseHybridHead, 3 stream-ordered kernels (R15):
//  KA: pre-GEMM -> per-sample RY factors fac[8192][20] f32 (c45,s45 x 10);
//      Arm rows (1024x1024 f16); zero z[8192][10].  [psi0 16MB write REMOVED]
//  KB: MFMA GEMM psif = psi0 @ Arm^T with A SYNTHESIZED on the fly:
//      psi0[s][k] = prod_w f_w[bit_{9-w}(k)] = PH(s,t)*PM(s,g)*PL(s,e) for
//      k = t*64+g*8+e. Per K-step each thread expands+ds_writes its 2 swizzled
//      granules (same LDS layout as R13's staged A -> compute() unchanged).
//      B: 3-deep global_load_lds pipeline, counted vmcnt(8/4/0). 128x256 tile,
//      8 waves, XCD-affinity remap [R14]. Fused measurement epilogue
//      [R13-verified signs] -> LDS combine -> atomicAdd z.
//  KC: out = z @ Wpost^T + bpost.                   [R6-verified]
//  Fallback: R1-verified single kernel for off-shape.

#define NQ   10
#define NREG 16
#define DIM  1024

typedef _Float16 f16;
typedef _Float16 f16x8 __attribute__((ext_vector_type(8)));
typedef float    f32x4 __attribute__((ext_vector_type(4)));

// ---------------------------------------------------------------- gate ops
template<int BB>
__device__ __forceinline__ void ry_lane(float (&s)[NREG], int lane, float c, float si) {
    float sgn = ((lane >> BB) & 1) ? si : -si;
    #pragma unroll
    for (int r = 0; r < NREG; ++r) {
        float o = __shfl_xor(s[r], 1 << BB);
        s[r] = fmaf(sgn, o, c * s[r]);
    }
}
template<int P>
__device__ __forceinline__ void ry_reg(float (&s)[NREG], float c, float si) {
    const int m = 1 << P;
    #pragma unroll
    for (int r = 0; r < NREG; ++r) {
        if ((r & m) == 0) {
            float a = s[r], b = s[r + m];
            s[r]     = fmaf(c, a, -si * b);
            s[r + m] = fmaf(si, a,  c * b);
        }
    }
}
__device__ __forceinline__ void cnot_5_6(float (&s)[NREG], int lane) {
    bool sel = (lane & 1) != 0;
    #pragma unroll
    for (int r = 0; r < 8; ++r) {
        float a = s[r], b = s[r + 8];
        s[r]     = sel ? b : a;
        s[r + 8] = sel ? a : b;
    }
}
template<int PC, int PT>
__device__ __forceinline__ void cnot_reg(float (&s)[NREG]) {
    #pragma unroll
    for (int r = 0; r < NREG; ++r) {
        if (((r >> PC) & 1) && !((r >> PT) & 1)) {
            float t = s[r];
            s[r] = s[r ^ (1 << PT)];
            s[r ^ (1 << PT)] = t;
        }
    }
}
__device__ __forceinline__ void perm_even(float (&s)[NREG], int lane) {
    int src = lane ^ (((((lane >> 5) & 1) << 4)) | ((((lane >> 3) & 1) << 2)) | (((lane >> 1) & 1)));
    #pragma unroll
    for (int r = 0; r < NREG; ++r) s[r] = __shfl(s[r], src);
}
__device__ __forceinline__ void perm_odd(float (&s)[NREG], int lane) {
    int src = lane ^ (((((lane >> 4) & 1) << 3)) | ((((lane >> 2) & 1) << 1)));
    #pragma unroll
    for (int r = 0; r < NREG; ++r) s[r] = __shfl(s[r], src);
}

#define APPLY_RY_ALL(CARR, SARR, BASE)                                        \
    { float c_, s_;                                                           \
      c_=__shfl(CARR,(BASE)+0); s_=__shfl(SARR,(BASE)+0); ry_lane<5>(s,lane,c_,s_); \
      c_=__shfl(CARR,(BASE)+1); s_=__shfl(SARR,(BASE)+1); ry_lane<4>(s,lane,c_,s_); \
      c_=__shfl(CARR,(BASE)+2); s_=__shfl(SARR,(BASE)+2); ry_lane<3>(s,lane,c_,s_); \
      c_=__shfl(CARR,(BASE)+3); s_=__shfl(SARR,(BASE)+3); ry_lane<2>(s,lane,c_,s_); \
      c_=__shfl(CARR,(BASE)+4); s_=__shfl(SARR,(BASE)+4); ry_lane<1>(s,lane,c_,s_); \
      c_=__shfl(CARR,(BASE)+5); s_=__shfl(SARR,(BASE)+5); ry_lane<0>(s,lane,c_,s_); \
      c_=__shfl(CARR,(BASE)+6); s_=__shfl(SARR,(BASE)+6); ry_reg<3>(s,c_,s_);       \
      c_=__shfl(CARR,(BASE)+7); s_=__shfl(SARR,(BASE)+7); ry_reg<2>(s,c_,s_);       \
      c_=__shfl(CARR,(BASE)+8); s_=__shfl(SARR,(BASE)+8); ry_reg<1>(s,c_,s_);       \
      c_=__shfl(CARR,(BASE)+9); s_=__shfl(SARR,(BASE)+9); ry_reg<0>(s,c_,s_); }

__device__ __forceinline__ void async16(const void* g, void* l) {
    __builtin_amdgcn_global_load_lds(
        (const __attribute__((address_space(1))) void*)g,
        (__attribute__((address_space(3))) void*)l, 16, 0, 0);
}

// raw barrier + scheduling fence; NO compiler vmcnt(0) drain.
#define BARRIER() do { __builtin_amdgcn_s_barrier(); __builtin_amdgcn_sched_barrier(0); } while (0)
#define VMCNT8()  asm volatile("s_waitcnt vmcnt(8)" ::: "memory")
#define VMCNT4()  asm volatile("s_waitcnt vmcnt(4)" ::: "memory")
#define VMCNT0()  asm volatile("s_waitcnt vmcnt(0)" ::: "memory")
#define LGKMCNT0() asm volatile("s_waitcnt lgkmcnt(0)" ::: "memory")

// ---------------------------------------------------------------- KA  [R15]
// grid 2048 x 256: one sample per wave -> fac[20]; blocks 0..511: 2 Arm rows.
__global__ __launch_bounds__(256) void ka_prepare(
    const float* __restrict__ X, const float* __restrict__ Wpre,
    const float* __restrict__ bpre, const float* __restrict__ qp,
    float* __restrict__ fac, f16* __restrict__ Arm, float* __restrict__ z, int B)
{
    const int tid = threadIdx.x, lane = tid & 63, wv = tid >> 6;

    // ---- zero z accumulator (8192*10 floats; 2048x256 threads cover 1/thread)
    {
        int idx = blockIdx.x * 256 + tid;
        if (idx < 8192 * NQ) z[idx] = 0.0f;
    }

    // ---- factors: one sample per wave
    {
        int sample = blockIdx.x * 4 + wv;
        if (sample < B) {
            const float* xrow = X + (size_t)sample * 512;
            float4 x0 = ((const float4*)xrow)[lane];
            float4 x1 = ((const float4*)xrow)[64 + lane];
            float acc[NQ];
            #pragma unroll
            for (int q = 0; q < NQ; ++q) {
                const float* wr = Wpre + q * 512;
                float4 w0 = ((const float4*)wr)[lane];
                float4 w1 = ((const float4*)wr)[64 + lane];
                float a = x0.x * w0.x;
                a = fmaf(x0.y, w0.y, a); a = fmaf(x0.z, w0.z, a); a = fmaf(x0.w, w0.w, a);
                a = fmaf(x1.x, w1.x, a); a = fmaf(x1.y, w1.y, a);
                a = fmaf(x1.z, w1.z, a); a = fmaf(x1.w, w1.w, a);
                acc[q] = a;
            }
            #pragma unroll
            for (int q = 0; q < NQ; ++q) {
                float v = acc[q];
                #pragma unroll
                for (int d = 32; d >= 1; d >>= 1) v += __shfl_xor(v, d);
                acc[q] = v;
            }
            float pre = acc[0];
            #pragma unroll
            for (int q = 1; q < NQ; ++q) pre = (lane == q) ? acc[q] : pre;
            if (lane < NQ) {
                float th = tanhf(pre + bpre[lane]) * 1.5707963267948966f;
                float s45, c45;
                sincosf(0.5f * th + 0.7853981633974483f, &s45, &c45);
                float* fp = fac + (size_t)sample * 20;
                fp[2 * lane]     = c45;
                fp[2 * lane + 1] = s45;
            }
        }
    }

    // ---- Arm rows: blocks 0..511, waves 0,1 build row (blockIdx*2 + wv)
    if (wv < 2) {
        int row = blockIdx.x * 2 + wv;
        if (row < DIM) {
            float cw = 1.0f, swn = 0.0f;
            if (lane < 60) {
                float s_, c_;
                sincosf(0.5f * qp[10 + lane], &s_, &c_);
                cw = c_; swn = -s_;
            }
            float s[NREG];
            int srcLane = row >> 4, srcReg = row & 15;
            #pragma unroll
            for (int r = 0; r < NREG; ++r)
                s[r] = (lane == srcLane && r == srcReg) ? 1.0f : 0.0f;
            for (int kk = 6; kk >= 1; --kk) {
                APPLY_RY_ALL(cw, swn, (kk - 1) * 10);
                perm_odd(s, lane);
                cnot_5_6(s, lane);
                cnot_reg<2, 1>(s);
                perm_even(s, lane);
                cnot_reg<3, 2>(s);
                cnot_reg<1, 0>(s);
            }
            union { f16 h[16]; float4 v[2]; } u;
            #pragma unroll
            for (int r = 0; r < NREG; ++r) u.h[r] = (f16)s[r];
            float4* dst = (float4*)((char*)Arm + (size_t)row * 2048 + lane * 32);
            dst[0] = u.v[0];
            dst[1] = u.v[1];
        }
    }
}

// ---------------------------------------------------------------- KB  [R15]
// 128x256 tile, BK=64, grid 256, 512 threads = 8 waves (2M x 4N, wave 64x64).
// A synthesized from factors into swizzled LDS (layout identical to staged
// version -> compute() untouched). B: 3-deep async pipeline, vmcnt(8/4/0).
__global__ __launch_bounds__(512) void kb_gemm_measure(
    const float* __restrict__ fac, const f16* __restrict__ Arm,
    float* __restrict__ z)
{
    __shared__ __align__(16) char smem[131072];  // A0|A1 16K ea, B0|B1|B2 32K ea
    const int tid = threadIdx.x, lane = tid & 63, wv = tid >> 6;
    // XCD-affinity: p%8 = XCD. Same-mB siblings share an XCD's L2. [R14]
    const int p = blockIdx.x;
    const int mB = (p & 7) + 8 * (p >> 5), nB = (p >> 3) & 3;
    const size_t tM = (size_t)mB * 128, tN = (size_t)nB * 256;
    f16* A0 = (f16*)smem;
    f16* A1 = (f16*)(smem + 16384);
    f16* B0 = (f16*)(smem + 32768);
    f16* B1 = (f16*)(smem + 65536);
    f16* B2 = (f16*)(smem + 98304);
    const int wm = (wv >> 2) * 64, wn = (wv & 3) * 64;

    f32x4 acc[4][4] = {};

    // ---- B staging: 2048 slots (4/thread); 8-f16 granules, XOR-swizzled.
    const f16* gb[4]; int ldsoB[4];
    #pragma unroll
    for (int q = 0; q < 4; ++q) {
        int slot = q * 512 + tid;
        int row = slot >> 3, gp = slot & 7, g = gp ^ (row & 7);
        gb[q] = Arm + (tN + row) * 1024 + g * 8;
        ldsoB[q] = slot * 16;
    }
    auto stageB = [&](f16* Bb, int t) {   // 4 loads/wave
        #pragma unroll
        for (int q = 0; q < 4; ++q) async16(gb[q] + t * 64, (char*)Bb + ldsoB[q]);
    };

    // ---- A synthesis state: 2 slots/thread (slot = q*512+tid).
    // slot -> row = slot>>3 (sample tM+row), gp = slot&7, g = gp^(row&7).
    // psi0[s][k], k = t*64 + g*8 + e:
    //   = PH(t) * PGL[e],  PH = f0[t3]*f1[t2]*f2[t1]*f3[t0]  (wires 0-3)
    //   PGL[e] = PM(g) * PL(e); PM over wires 4,5,6 (g bits 2,1,0),
    //                           PL over wires 7,8,9 (e bits 2,1,0).
    float c0[2], s0[2], c1[2], s1[2], c2[2], s2[2], c3[2], s3[2];
    float pgl[2][8];
    int ldsoA[2];
    #pragma unroll
    for (int q = 0; q < 2; ++q) {
        int slot = q * 512 + tid;
        int row = slot >> 3, gp = slot & 7, g = gp ^ (row & 7);
        ldsoA[q] = slot * 16;
        const float* fp = fac + (tM + row) * 20;
        float4 f01 = ((const float4*)fp)[0];  // c0 s0 c1 s1
        float4 f23 = ((const float4*)fp)[1];  // c2 s2 c3 s3
        float4 f45 = ((const float4*)fp)[2];  // c4 s4 c5 s5
        float4 f67 = ((const float4*)fp)[3];  // c6 s6 c7 s7
        float4 f89 = ((const float4*)fp)[4];  // c8 s8 c9 s9
        c0[q] = f01.x; s0[q] = f01.y; c1[q] = f01.z; s1[q] = f01.w;
        c2[q] = f23.x; s2[q] = f23.y; c3[q] = f23.z; s3[q] = f23.w;
        float pm = (((g >> 2) & 1) ? f45.y : f45.x)
                 * (((g >> 1) & 1) ? f45.w : f45.z)
                 * ((g & 1)        ? f67.y : f67.x);
        #pragma unroll
        for (int e = 0; e < 8; ++e) {
            pgl[q][e] = pm * (((e >> 2) & 1) ? f67.w : f67.z)
                           * (((e >> 1) & 1) ? f89.y : f89.x)
                           * ((e & 1)        ? f89.w : f89.z);
        }
    }
    auto writeA = [&](f16* Ab, int t) {
        #pragma unroll
        for (int q = 0; q < 2; ++q) {
            float ph = ((t & 8) ? s0[q] : c0[q]) * ((t & 4) ? s1[q] : c1[q])
                     * ((t & 2) ? s2[q] : c2[q]) * ((t & 1) ? s3[q] : c3[q]);
            f16x8 v;
            #pragma unroll
            for (int e = 0; e < 8; ++e) v[e] = (f16)(ph * pgl[q][e]);
            *(f16x8*)((char*)Ab + ldsoA[q]) = v;
        }
    };

    auto compute = [&](const f16* Ab, const f16* Bb) {
        #pragma unroll
        for (int ks = 0; ks < 2; ++ks) {
            f16x8 af[4], bf[4];
            const int gpb = ks * 4 + (lane >> 4);
            const int gpx = gpb ^ (lane & 7);
            #pragma unroll
            for (int i = 0; i < 4; ++i) {
                int rowA = wm + i * 16 + (lane & 15);
                af[i] = *(const f16x8*)(Ab + rowA * 64 + gpx * 8);
            }
            #pragma unroll
            for (int j = 0; j < 4; ++j) {
                int rowB = wn + j * 16 + (lane & 15);
                bf[j] = *(const f16x8*)(Bb + rowB * 64 + gpx * 8);
            }
            #pragma unroll
            for (int i = 0; i < 4; ++i)
                #pragma unroll
                for (int j = 0; j < 4; ++j)
                    acc[i][j] = __builtin_amdgcn_mfma_f32_16x16x32_f16(af[i], bf[j], acc[i][j], 0, 0, 0);
        }
    };

    // 3-deep B pipeline over 16 K-tiles; A written per-parity each iter.
    f16 *Bc = B0, *Bn = B1, *Bf = B2;
    stageB(Bc, 0);
    stageB(Bn, 1);
    #pragma unroll 1
    for (int t = 0; t < 14; ++t) {
        stageB(Bf, t + 2);            // 12 B-loads in flight
        writeA((t & 1) ? A1 : A0, t); // overlap expansion with B-load wait
        VMCNT8();                     // own 4 oldest (tile-t B) retired
        LGKMCNT0();                   // A ds_writes visible
        BARRIER();
        compute((t & 1) ? A1 : A0, Bc);
        BARRIER();
        f16* tmp = Bc; Bc = Bn; Bn = Bf; Bf = tmp;
    }
    writeA(A0, 14);
    VMCNT4(); LGKMCNT0(); BARRIER();
    compute(A0, Bc);
    BARRIER();
    writeA(A1, 15);
    VMCNT0(); LGKMCNT0(); BARRIER();
    compute(A1, Bn);

    // ---- fused +-square measurement epilogue [R13-verified] ----
    // psif col n = tN + wn + j*16 + (lane&15): n9:8 <- nB, n7:6 <- wv&3,
    // n5:4 <- j, n3:0 <- lane&15. wires 0..9 <- n bits 9..0.
    __syncthreads();  // done with LDS; reuse as zbuf[4][128][10] f32 (20KB)
    float* zbuf = (float*)smem;
    float* zb = zbuf + (wv & 3) * 1280;
    const float sg0 = (nB & 2)        ? -1.0f : 1.0f;  // wire0 <- n9
    const float sg1 = (nB & 1)        ? -1.0f : 1.0f;  // wire1 <- n8
    const float sg2 = ((wv >> 1) & 1) ? -1.0f : 1.0f;  // wire2 <- n7
    const float sg3 = (wv & 1)        ? -1.0f : 1.0f;  // wire3 <- n6

    #pragma unroll
    for (int i = 0; i < 4; ++i) {
        #pragma unroll
        for (int t = 0; t < 4; ++t) {
            float p0 = acc[i][0][t] * acc[i][0][t];
            float p1 = acc[i][1][t] * acc[i][1][t];
            float p2 = acc[i][2][t] * acc[i][2][t];
            float p3 = acc[i][3][t] * acc[i][3][t];
            float t0  = (p0 + p1) + (p2 + p3);
            float tw5 = (p0 - p1) + (p2 - p3);  // wire5 <- n4 = j&1
            float tw4 = (p0 + p1) - (p2 + p3);  // wire4 <- n5 = j>>1
            // butterfly over lane bits 0..3 = n[3..0] -> wires 6,7,8,9
            float s1_ = __shfl_xor(t0, 1);
            float Av = t0 + s1_;
            float Bv = (lane & 1) ? s1_ - t0 : t0 - s1_;
            float sA = __shfl_xor(Av, 2), sB = __shfl_xor(Bv, 2);
            float AP = Av + sA;
            float AM = (lane & 2) ? sA - Av : Av - sA;
            float BP = Bv + sB;
            float sAP = __shfl_xor(AP, 4), sAM = __shfl_xor(AM, 4), sBP = __shfl_xor(BP, 4);
            float APP = AP + sAP;
            float APM = (lane & 4) ? sAP - AP : AP - sAP;
            float AMP = AM + sAM;
            float BPP = BP + sBP;
            float a1 = __shfl_xor(APP, 8), a2 = __shfl_xor(APM, 8);
            float a3 = __shfl_xor(AMP, 8), a4 = __shfl_xor(BPP, 8);
            float T0 = APP + a1;
            float S6 = (lane & 8) ? a1 - APP : APP - a1;
            float S7 = APM + a2;
            float S8 = AMP + a3;
            float S9 = BPP + a4;
            float T5 = tw5, T4 = tw4;
            T5 += __shfl_xor(T5, 1); T5 += __shfl_xor(T5, 2);
            T5 += __shfl_xor(T5, 4); T5 += __shfl_xor(T5, 8);
            T4 += __shfl_xor(T4, 1); T4 += __shfl_xor(T4, 2);
            T4 += __shfl_xor(T4, 4); T4 += __shfl_xor(T4, 8);
            if ((lane & 15) == 0) {
                int row = wm + i * 16 + (lane >> 4) * 4 + t;
                float* d = zb + row * 10;
                d[0] = sg0 * T0; d[1] = sg1 * T0; d[2] = sg2 * T0; d[3] = sg3 * T0;
                d[4] = T4; d[5] = T5;
                d[6] = S6; d[7] = S7; d[8] = S8; d[9] = S9;
            }
        }
    }
    __syncthreads();
    // combine 4 col-quarters, atomic-accumulate into z[tM+row][10]
    for (int idx = tid; idx < 1280; idx += 512) {
        float v = (zbuf[idx] + zbuf[1280 + idx]) + (zbuf[2560 + idx] + zbuf[3840 + idx]);
        int row = idx / 10, w = idx - row * 10;
        atomicAdd(&z[((size_t)tM + row) * 10 + w], v);
    }
}

// ---------------------------------------------------------------- KC  [R6-verified]
__global__ __launch_bounds__(256) void kc_post(
    const float* __restrict__ z, const float* __restrict__ Wpost,
    const float* __restrict__ bpost, float* __restrict__ out, int B)
{
    int gid = blockIdx.x * 256 + threadIdx.x;
    if (gid >= B) return;
    const float* zp = z + (size_t)gid * NQ;
    float o0 = bpost[0], o1 = bpost[1];
    #pragma unroll
    for (int w = 0; w < NQ; ++w) {
        float zw = zp[w];
        o0 = fmaf(zw, Wpost[w], o0);
        o1 = fmaf(zw, Wpost[NQ + w], o1);
    }
    out[(size_t)gid * 2 + 0] = o0;
    out[(size_t)gid * 2 + 1] = o1;
}

// ---------------------------------------------------------------- fallback (R1, verified)
template<int BC, int BT>
__device__ __forceinline__ void cnot_lane(float (&s)[NREG], int lane) {
    int src = ((lane >> BC) & 1) ? (lane ^ (1 << BT)) : lane;
    #pragma unroll
    for (int r = 0; r < NREG; ++r) s[r] = __shfl(s[r], src);
}

__global__ __launch_bounds__(256) void hybrid_head_fallback(
    const float* __restrict__ X, const float* __restrict__ Wpre,
    const float* __restrict__ bpre, const float* __restrict__ qp,
    const float* __restrict__ Wpost, const float* __restrict__ bpost,
    float* __restrict__ out, int B)
{
    const int lane = threadIdx.x & 63;
    const int wave = threadIdx.x >> 6;
    const int sample = blockIdx.x * 4 + wave;
    if (sample >= B) return;

    const float* xrow = X + (size_t)sample * 512;
    float4 x0 = ((const float4*)xrow)[lane];
    float4 x1 = ((const float4*)xrow)[64 + lane];
    float acc[NQ];
    #pragma unroll
    for (int q = 0; q < NQ; ++q) {
        const float* wr = Wpre + q * 512;
        float4 w0 = ((const float4*)wr)[lane];
        float4 w1 = ((const float4*)wr)[64 + lane];
        float a = x0.x * w0.x;
        a = fmaf(x0.y, w0.y, a); a = fmaf(x0.z, w0.z, a); a = fmaf(x0.w, w0.w, a);
        a = fmaf(x1.x, w1.x, a); a = fmaf(x1.y, w1.y, a);
        a = fmaf(x1.z, w1.z, a); a = fmaf(x1.w, w1.w, a);
        acc[q] = a;
    }
    #pragma unroll
    for (int q = 0; q < NQ; ++q) {
        float v = acc[q];
        #pragma unroll
        for (int d = 32; d >= 1; d >>= 1) v += __shfl_xor(v, d);
        acc[q] = v;
    }
    float pre = acc[0];
    #pragma unroll
    for (int q = 1; q < NQ; ++q) pre = (lane == q) ? acc[q] : pre;
    float cth = 1.0f, sth = 0.0f;
    if (lane < NQ) {
        float th = tanhf(pre + bpre[lane]) * 1.5707963267948966f;
        sincosf(0.5f * th, &sth, &cth);
    }
    float cw = 1.0f, sw = 0.0f;
    if (lane < 60) sincosf(0.5f * qp[10 + lane], &sw, &cw);

    float s[NREG];
    #pragma unroll
    for (int r = 0; r < NREG; ++r) s[r] = 0.03125f;
    APPLY_RY_ALL(cth, sth, 0);
    for (int k = 0; k < 6; ++k) {
        perm_even(s, lane);
        cnot_reg<3, 2>(s);
        cnot_reg<1, 0>(s);
        perm_odd(s, lane);
        cnot_5_6(s, lane);
        cnot_reg<2, 1>(s);
        APPLY_RY_ALL(cw, sw, k * 10);
    }
    float p[NREG], tot = 0.0f;
    #pragma unroll
    for (int r = 0; r < NREG; ++r) { p[r] = s[r] * s[r]; tot += p[r]; }
    float z[NQ];
    #pragma unroll
    for (int w = 0; w < 6; ++w) z[w] = ((lane >> (5 - w)) & 1) ? -tot : tot;
    z[6] = z[7] = z[8] = z[9] = 0.0f;
    #pragma unroll
    for (int r = 0; r < NREG; ++r) {
        z[6] += ((r >> 3) & 1) ? -p[r] : p[r];
        z[7] += ((r >> 2) & 1) ? -p[r] : p[r];
        z[8] += ((r >> 1) & 1) ? -p[r] : p[r];
        z[9] += ((r >> 0) & 1) ? -p[r] : p[r];
    }
    #pragma unroll
    for (int w = 0; w < NQ; ++w) {
        float v = z[w];
        #pragma unroll
        for (int d = 32; d >= 1; d >>= 1) v += __shfl_xor(v, d);
        z[w] = v;
    }
    if (lane < 2) {
        const float* wp = Wpost + lane * NQ;
        float o = bpost[lane];
        #pragma unroll
        for (int w = 0; w < NQ; ++w) o = fmaf(z[w], wp[w], o);
        out[(size_t)sample * 2 + lane] = o;
    }
}

// ---------------------------------------------------------------- launch
extern "C" void kernel_launch(void* const* d_in, const int* in_sizes, int n_in,
                              void* d_out, int out_size, void* d_ws, size_t ws_size,
                              hipStream_t stream) {
    const float* X     = (const float*)d_in[0];
    const float* Wpre  = (const float*)d_in[1];
    const float* bpre  = (const float*)d_in[2];
    const float* qp    = (const float*)d_in[3];
    const float* Wpost = (const float*)d_in[4];
    const float* bpost = (const float*)d_in[5];
    float* out = (float*)d_out;
    int B = in_sizes[0] / 512;  // 8192

    size_t fac_b  = (size_t)B * 20 * sizeof(float);     // 640 KB
    size_t arm_b  = (size_t)DIM * DIM * sizeof(f16);    // 2 MB
    size_t z_b    = (size_t)B * NQ * sizeof(float);     // 320 KB
    size_t need = fac_b + arm_b + z_b;

    if (B != 8192 || ws_size < need) {
        hipLaunchKernelGGL(hybrid_head_fallback, dim3((B + 3) / 4), dim3(256), 0, stream,
                           X, Wpre, bpre, qp, Wpost, bpost, out, B);
        return;
    }

    char* ws = (char*)d_ws;
    float* fac = (float*)ws;
    f16*   Arm = (f16*)(ws + fac_b);
    float* z   = (float*)(ws + fac_b + arm_b);

    hipLaunchKernelGGL(ka_prepare, dim3(2048), dim3(256), 0, stream,
                       X, Wpre, bpre, qp, fac, Arm, z, B);
    hipLaunchKernelGGL(kb_gemm_measure, dim3(256), dim3(512), 0, stream,
                       fac, Arm, z);
    hipLaunchKernelGGL(kc_post, dim3(32), dim3(256), 0, stream,
                       z, Wpost, bpost, out, B);
}